// Round 9
// baseline (278.286 us; speedup 1.0000x reference)
//
#include <hip/hip_runtime.h>

// Problem constants: B=2, S=128, L=R=H=8, D=64. Tokens = 256.
//
// Session ledger:
//  R2/R6: 1024-thread blocks get VGPR-squeezed below the declared bound ->
//         spill catastrophe. Use 512-thread blocks for big bodies.
//  R3/R4: hipLaunchCooperativeKernel silently no-ops under this harness
//         (output never written; bit-identical absmax across binaries).
//         Regular <<<>>> launches work fine.
//  R5-R8: attn ladder: v3 4q=71.6 BEST; 8q variants 82.6-91.0 (VGPR
//         pressure), VALUBusy pinned ~56% throughout.
//  Invariant: non-attn time ~96+-5 us across 5 proj structures; proj
//         compute model says ~20-25 us -> suspect per-dispatch overhead.
//  R9 (this): ONE regular kernel, 512 blocks x 512 thr, 66.5 KB LDS ->
//         exactly 2 blocks/CU x 256 CU co-resident -> non-cooperative
//         device-atomic grid barrier (R4 design, bounded spin).
//         P1 proj(q,k)+proj(v) -> bar -> P2 v3 attn -> bar -> P3 out proj.
//         All math byte-identical to the R0-verified kernels.

#define NBLK 512u
#define SPIN_LIMIT 100000000u

__device__ unsigned g_cnt[2];   // zero-initialized at module load; monotone

__device__ __forceinline__ void grid_barrier(int which) {
    __syncthreads();   // block's stores drained (vmcnt 0 before barrier)
    if (threadIdx.x == 0) {
        __threadfence();                       // release: XCD L2 writeback
        unsigned old = atomicAdd(&g_cnt[which], 1u);
        const unsigned target = (old / NBLK + 1u) * NBLK;
        unsigned spins = 0;
        while (__hip_atomic_load(&g_cnt[which], __ATOMIC_ACQUIRE,
                                 __HIP_MEMORY_SCOPE_AGENT) < target) {
            if (++spins > SPIN_LIMIT) break;   // safety valve: fail visibly
        }
        __threadfence();                       // acquire: invalidate L1/L2
    }
    __syncthreads();
}

// ---------------------------------------------------------------------------
// proj_tile_512: the PROVEN 256-thread proj_tile body run inside a
// 512-thread block. Staging uses all 512 threads (2 float4 each); compute
// masks tid<256 with the exact R0 per-thread arithmetic (same FLOP order ->
// same bits). All __syncthreads are uniform (outside the active masks).
// dst = (Wl^T @ X @ Wr + bias) * 0.125 for one 64x64 token.
// ---------------------------------------------------------------------------
__device__ __forceinline__ void proj_tile_512(
    const float* __restrict__ src, const float* __restrict__ wl,
    const float* __restrict__ wr, const float* __restrict__ bias,
    float* __restrict__ dst, const bool active,
    float* Xs, float* Wls, float* Wrs, float* Ts /* 64 x 68 padded */)
{
    const int tid = threadIdx.x;

    if (active) {
        float4* X4 = (float4*)Xs;
        float4* L4 = (float4*)Wls;
        float4* R4 = (float4*)Wrs;
        const float4* sx = (const float4*)src;
        const float4* sl = (const float4*)wl;
        const float4* sr = (const float4*)wr;
        #pragma unroll
        for (int i = 0; i < 2; ++i) {
            const int idx = tid + i * 512;
            X4[idx] = sx[idx];
            L4[idx] = sl[idx];
            R4[idx] = sr[idx];
        }
    }
    __syncthreads();

    const int n4 = tid >> 4;        // (only meaningful for tid<256)
    const int m4 = tid & 15;
    const int c0 = (n4 & 15) << 2;

    if (active && tid < 256) {
        // Pass 1: T[c][b] = sum_a Wl[a][c] * X[a][b]
        float a_[4][4];
        #pragma unroll
        for (int i = 0; i < 4; ++i)
            #pragma unroll
            for (int j = 0; j < 4; ++j) a_[i][j] = 0.f;

        for (int a = 0; a < 64; ++a) {
            float4 wlv = ((const float4*)(Wls + a * 64))[n4];
            float4 xv  = ((const float4*)(Xs  + a * 64))[m4];
            float wlf[4] = {wlv.x, wlv.y, wlv.z, wlv.w};
            float xf[4]  = {xv.x, xv.y, xv.z, xv.w};
            #pragma unroll
            for (int i = 0; i < 4; ++i)
                #pragma unroll
                for (int j = 0; j < 4; ++j) a_[i][j] += wlf[i] * xf[j];
        }
        #pragma unroll
        for (int i = 0; i < 4; ++i)
            *(float4*)(Ts + (c0 + i) * 68 + (m4 << 2)) =
                make_float4(a_[i][0], a_[i][1], a_[i][2], a_[i][3]);
    }
    __syncthreads();

    if (active && tid < 256) {
        // Pass 2: Y[c][d] = sum_b T[c][b] * Wr[b][d]
        float y_[4][4];
        #pragma unroll
        for (int i = 0; i < 4; ++i)
            #pragma unroll
            for (int j = 0; j < 4; ++j) y_[i][j] = 0.f;

        for (int bq = 0; bq < 16; ++bq) {
            float tvf[4][4];
            #pragma unroll
            for (int i = 0; i < 4; ++i) {
                float4 t = *(const float4*)(Ts + (c0 + i) * 68 + (bq << 2));
                tvf[i][0] = t.x; tvf[i][1] = t.y; tvf[i][2] = t.z; tvf[i][3] = t.w;
            }
            float wvf[4][4];
            #pragma unroll
            for (int jj = 0; jj < 4; ++jj) {
                float4 w = ((const float4*)(Wrs + ((bq << 2) + jj) * 64))[m4];
                wvf[jj][0] = w.x; wvf[jj][1] = w.y; wvf[jj][2] = w.z; wvf[jj][3] = w.w;
            }
            #pragma unroll
            for (int i = 0; i < 4; ++i)
                #pragma unroll
                for (int jj = 0; jj < 4; ++jj)
                    #pragma unroll
                    for (int j = 0; j < 4; ++j)
                        y_[i][j] += tvf[i][jj] * wvf[jj][j];
        }

        #pragma unroll
        for (int i = 0; i < 4; ++i) {
            const int off = (c0 + i) * 64 + (m4 << 2);
            float4 bv = *(const float4*)(bias + off);
            float4 o;
            o.x = (y_[i][0] + bv.x) * 0.125f;
            o.y = (y_[i][1] + bv.y) * 0.125f;
            o.z = (y_[i][2] + bv.z) * 0.125f;
            o.w = (y_[i][3] + bv.w) * 0.125f;
            *(float4*)(dst + off) = o;
        }
    }
    __syncthreads();   // Ts/Wrs reads done before next staging overwrites
}

// ---------------------------------------------------------------------------
// Fused pipeline: one regular kernel.
// ---------------------------------------------------------------------------
__global__ __launch_bounds__(512, 2) void fused_kernel(
    const float* __restrict__ q_in, const float* __restrict__ k_in, const float* __restrict__ v_in,
    const float* __restrict__ wql, const float* __restrict__ wqr, const float* __restrict__ bq,
    const float* __restrict__ wkl, const float* __restrict__ wkr, const float* __restrict__ bk,
    const float* __restrict__ wvl, const float* __restrict__ wvr, const float* __restrict__ bv,
    const float* __restrict__ wol, const float* __restrict__ wor, const float* __restrict__ bo,
    float* __restrict__ out, float* __restrict__ Qp, float* __restrict__ Kp, float* __restrict__ Vp)
{
    __shared__ float smem[16640];   // 66,560 B; 2 blocks/CU (133 KB <= 160 KB)
    float* Xs  = smem;              // 4096   (attn: Ks = smem[0..8191])
    float* Wls = smem + 4096;       // 4096
    float* Wrs = smem + 8192;       // 4096   (attn: Vs = smem[8192..16383])
    float* Ts  = smem + 12288;      // 4352 = 64*68

    const int bid = blockIdx.x;     // 0..511
    const int tid = threadIdx.x;

    // ---- P1 round 1: blocks 0-255 -> Q proj of token bid; 256-511 -> K proj.
    {
        const int t = bid & 255;
        const bool isq = bid < 256;
        proj_tile_512(isq ? q_in + t * 4096 : k_in + t * 4096,
                      isq ? wql : wkl, isq ? wqr : wkr, isq ? bq : bk,
                      (isq ? Qp : Kp) + t * 4096, true, Xs, Wls, Wrs, Ts);
    }
    // ---- P1 round 2: blocks 0-255 -> V proj of token bid; others idle.
    {
        const int t = bid & 255;
        proj_tile_512(v_in + t * 4096, wvl, wvr, bv, Vp + t * 4096,
                      bid < 256, Xs, Wls, Wrs, Ts);
    }

    grid_barrier(0);

    // ---- P2: attention, verbatim v3 body (71.6 us, 0 bank conflicts).
    {
        float* Ks = smem;           // 8192 floats
        float* Vs = smem + 8192;    // 8192 floats

        const int chunk = bid & 3;
        const int r = (bid >> 2) & 7;
        const int l = (bid >> 5) & 7;
        const int b = bid >> 8;

        for (int f = tid; f < 2048; f += 512) {
            const int k = f >> 4, rem = f & 15, yy = rem >> 1, hh = rem & 1;
            const int off = ((b * 128 + k) * 64 + (l * 8 + yy)) * 64 + (r * 8) + (hh << 2);
            *(float4*)(Ks + k * 64 + yy * 8 + (hh << 2)) = *(const float4*)(Kp + off);
            *(float4*)(Vs + k * 64 + yy * 8 + (hh << 2)) = *(const float4*)(Vp + off);
        }

        const int y = tid & 7;
        const int x = (tid >> 3) & 7;
        const int g = tid >> 6;
        const int sq0 = chunk * 32 + g * 4;

        const float sc = 0.125f;
        float q[4][8];
        #pragma unroll
        for (int i = 0; i < 4; ++i) {
            const float* qptr = Qp + (size_t)((b * 128 + sq0 + i) * 64 + (l * 8 + x)) * 64 + r * 8;
            float4 qa = *(const float4*)qptr;
            float4 qb = *(const float4*)(qptr + 4);
            q[i][0] = qa.x * sc; q[i][1] = qa.y * sc; q[i][2] = qa.z * sc; q[i][3] = qa.w * sc;
            q[i][4] = qb.x * sc; q[i][5] = qb.y * sc; q[i][6] = qb.z * sc; q[i][7] = qb.w * sc;
        }

        float Z[4];
        float num[4][8];
        #pragma unroll
        for (int i = 0; i < 4; ++i) {
            Z[i] = 0.f;
            #pragma unroll
            for (int e = 0; e < 8; ++e) num[i][e] = 0.f;
        }

        __syncthreads();

        const float* Krow = Ks + y * 8;
        const float* Vrow = Vs + y * 8;
        const float c3 = 1.0f / 6.0f;
        for (int k = 0; k < 128; ++k) {
            float4 ka = *(const float4*)(Krow + k * 64);
            float4 kb = *(const float4*)(Krow + k * 64 + 4);
            float4 va = *(const float4*)(Vrow + k * 64);
            float4 vb = *(const float4*)(Vrow + k * 64 + 4);
            #pragma unroll
            for (int i = 0; i < 4; ++i) {
                float t = q[i][0] * ka.x + q[i][1] * ka.y + q[i][2] * ka.z + q[i][3] * ka.w
                        + q[i][4] * kb.x + q[i][5] * kb.y + q[i][6] * kb.z + q[i][7] * kb.w;
                float p = __builtin_fmaf(t, c3, 0.5f);
                p = __builtin_fmaf(t, p, 1.0f);
                float w = __builtin_fmaf(t, p, 1.0f);
                Z[i] += w;
                num[i][0] += w * va.x; num[i][1] += w * va.y;
                num[i][2] += w * va.z; num[i][3] += w * va.w;
                num[i][4] += w * vb.x; num[i][5] += w * vb.y;
                num[i][6] += w * vb.z; num[i][7] += w * vb.w;
            }
        }

        #pragma unroll
        for (int i = 0; i < 4; ++i) {
            float iz = 1.0f / Z[i];
            #pragma unroll
            for (int e = 0; e < 8; ++e) num[i][e] *= iz;
        }

        #pragma unroll
        for (int m = 1; m <= 4; m <<= 1) {
            #pragma unroll
            for (int i = 0; i < 4; ++i) {
                #pragma unroll
                for (int e = 0; e < 8; ++e)
                    num[i][e] += __shfl_xor(num[i][e], m, 64);
            }
        }

        #pragma unroll
        for (int i = 0; i < 4; ++i) {
            if (y == i) {
                float* optr = Qp + (size_t)((b * 128 + sq0 + i) * 64 + (l * 8 + x)) * 64 + r * 8;
                *(float4*)optr       = make_float4(num[i][0], num[i][1], num[i][2], num[i][3]);
                *(float4*)(optr + 4) = make_float4(num[i][4], num[i][5], num[i][6], num[i][7]);
            }
        }
    }

    grid_barrier(1);

    // ---- P3: output projection; blocks 0-255 active, token bid.
    {
        const int t = bid & 255;
        proj_tile_512(Qp + t * 4096, wol, wor, bo, out + t * 4096,
                      bid < 256, Xs, Wls, Wrs, Ts);
    }
}

// ---------------------------------------------------------------------------
extern "C" void kernel_launch(void* const* d_in, const int* in_sizes, int n_in,
                              void* d_out, int out_size, void* d_ws, size_t ws_size,
                              hipStream_t stream) {
    (void)in_sizes; (void)n_in; (void)out_size; (void)ws_size;
    const float* q_in = (const float*)d_in[0];
    const float* k_in = (const float*)d_in[1];
    const float* v_in = (const float*)d_in[2];
    const float* wql = (const float*)d_in[3];
    const float* wqr = (const float*)d_in[4];
    const float* bq  = (const float*)d_in[5];
    const float* wkl = (const float*)d_in[6];
    const float* wkr = (const float*)d_in[7];
    const float* bk  = (const float*)d_in[8];
    const float* wvl = (const float*)d_in[9];
    const float* wvr = (const float*)d_in[10];
    const float* bv  = (const float*)d_in[11];
    const float* wol = (const float*)d_in[12];
    const float* wor = (const float*)d_in[13];
    const float* bo  = (const float*)d_in[14];
    float* out = (float*)d_out;

    float* Qp = (float*)d_ws;            // 256*4096 floats = 4 MiB
    float* Kp = Qp + 256 * 4096;
    float* Vp = Kp + 256 * 4096;

    fused_kernel<<<512, 512, 0, stream>>>(q_in, k_in, v_in,
                                          wql, wqr, bq,
                                          wkl, wkr, bk,
                                          wvl, wvr, bv,
                                          wol, wor, bo,
                                          out, Qp, Kp, Vp);
}